// Round 1
// 529.873 us; speedup vs baseline: 1.0632x; 1.0632x over previous
//
#include <hip/hip_runtime.h>
#include <hip/hip_bf16.h>
#include <stdint.h>

#define B_ 256
#define T_ 512
#define V_ 30000
#define E_ 256
#define H_ 32

typedef float v2f __attribute__((ext_vector_type(2)));

// ---------------------------------------------------------------------------
// Fast activations (fp32, saturate cleanly at extremes: no NaN)
// ---------------------------------------------------------------------------
__device__ __forceinline__ float sigmoidf_fast(float x) {
    return 1.0f / (1.0f + __expf(-x));
}
__device__ __forceinline__ float tanhf_fast(float x) {
    return 1.0f - 2.0f / (1.0f + __expf(2.0f * x));
}
// packed fp32 FMA, all-VGPR operands: acc.{lo,hi} += w.{lo,hi} * h.{lo,hi}
__device__ __forceinline__ void pk_fma(v2f& acc, v2f w, v2f h) {
    asm("v_pk_fma_f32 %0, %1, %2, %0" : "+v"(acc) : "v"(w), "v"(h));
}

// ---------------------------------------------------------------------------
// GEMM: Out[M,192] = A[M,K] @ Wcat[192,K]^T + bias   (unchanged)
// ---------------------------------------------------------------------------
#define GEMM_MT 64
#define GEMM_KC 32
#define GEMM_PA 68
#define GEMM_PB 196

__global__ __launch_bounds__(256) void gemm_gates(
    const float* __restrict__ A, int M, int K,
    const float* __restrict__ Wf, const float* __restrict__ Wb,
    const float* __restrict__ bihf, const float* __restrict__ bhhf,
    const float* __restrict__ bihb, const float* __restrict__ bhhb,
    float* __restrict__ Out)
{
    __shared__ float As[GEMM_KC][GEMM_PA];
    __shared__ float Bs[GEMM_KC][GEMM_PB];

    const int tid = threadIdx.x;
    const int mbase = blockIdx.x * GEMM_MT;
    const int mg = tid >> 5, ng = tid & 31;
    const int m_off = mg * 8, n_off = ng * 6;

    float acc[8][6];
    #pragma unroll
    for (int r = 0; r < 8; ++r)
        #pragma unroll
        for (int c = 0; c < 6; ++c) acc[r][c] = 0.f;

    for (int kc = 0; kc < K; kc += GEMM_KC) {
        #pragma unroll
        for (int i = 0; i < 2; ++i) {
            int fi = tid + 256 * i;
            int row = fi >> 3, cf = fi & 7;
            int m = mbase + row;
            float4 v = make_float4(0.f, 0.f, 0.f, 0.f);
            if (m < M) v = *(const float4*)&A[(size_t)m * K + kc + cf * 4];
            As[cf * 4 + 0][row] = v.x; As[cf * 4 + 1][row] = v.y;
            As[cf * 4 + 2][row] = v.z; As[cf * 4 + 3][row] = v.w;
        }
        #pragma unroll
        for (int i = 0; i < 6; ++i) {
            int fi = tid + 256 * i;
            int g = fi >> 3, cf = fi & 7;
            const float* Wsel = (g < 96) ? (Wf + (size_t)g * K)
                                         : (Wb + (size_t)(g - 96) * K);
            float4 v = *(const float4*)&Wsel[kc + cf * 4];
            Bs[cf * 4 + 0][g] = v.x; Bs[cf * 4 + 1][g] = v.y;
            Bs[cf * 4 + 2][g] = v.z; Bs[cf * 4 + 3][g] = v.w;
        }
        __syncthreads();
        #pragma unroll
        for (int k = 0; k < GEMM_KC; ++k) {
            float a[8], bb[6];
            *(float4*)&a[0] = *(const float4*)&As[k][m_off];
            *(float4*)&a[4] = *(const float4*)&As[k][m_off + 4];
            *(float2*)&bb[0] = *(const float2*)&Bs[k][n_off];
            *(float2*)&bb[2] = *(const float2*)&Bs[k][n_off + 2];
            *(float2*)&bb[4] = *(const float2*)&Bs[k][n_off + 4];
            #pragma unroll
            for (int r = 0; r < 8; ++r)
                #pragma unroll
                for (int c = 0; c < 6; ++c)
                    acc[r][c] = fmaf(a[r], bb[c], acc[r][c]);
        }
        __syncthreads();
    }

    float bias[6];
    #pragma unroll
    for (int c = 0; c < 6; ++c) {
        int g = n_off + c;
        int g96 = (g < 96) ? g : g - 96;
        const float* bih = (g < 96) ? bihf : bihb;
        const float* bhh = (g < 96) ? bhhf : bhhb;
        bias[c] = bih[g96] + ((g96 < 64) ? bhh[g96] : 0.f);
    }
    #pragma unroll
    for (int r = 0; r < 8; ++r) {
        int m = mbase + m_off + r;
        if (m < M) {
            float* op = &Out[(size_t)m * 192 + n_off];
            #pragma unroll
            for (int c = 0; c < 6; ++c) op[c] = acc[r][c] + bias[c];
        }
    }
}

// ---------------------------------------------------------------------------
// GRU scan. One wave per (batch-PAIR, direction): lanes 0-31 run batch b0,
// lanes 32-63 run batch b1 (same direction -> shared Whh rows per lane j).
// h[j] lives in lane (half*32+j). Broadcast of h within each half goes
// through LDS (1 ds_write_b32 + 8 broadcast ds_read_b128, conflict-free),
// yielding per-lane VGPR copies of h -> the recurrent matvec is 48
// v_pk_fma_f32 with all-VGPR operands (no v_readlane, no SGPR hazards).
// Two independent recurrences interleave in one wave: dependency stalls of
// one chain are filled by the other + by the 3 gate chains' ILP.
// gi prefetch: 128 chunks of 4 steps, two register banks alternate per chunk
// (4-body distance, no copy ever reads an in-flight load).
// ---------------------------------------------------------------------------
template <int USE_IDS>
__global__ __launch_bounds__(64, 1) void gru_scan(
    const float* __restrict__ gi,     // [rows,192]: G0 (gather) or gi1 (direct)
    const int* __restrict__ ids,
    const int* __restrict__ mask,
    const float* __restrict__ Whh_f, const float* __restrict__ Whh_b,
    const float* __restrict__ bhh_f, const float* __restrict__ bhh_b,
    float* __restrict__ out_seq,      // [B,T,64] or nullptr
    float* __restrict__ out_fin)      // [B,64]   or nullptr
{
    __shared__ float hsh[64];

    const int l = threadIdx.x;
    const int j = l & 31;
    const int half = l >> 5;                      // 0 -> b0, 1 -> b1
    const int dir = blockIdx.x & 1;
    const int b = (blockIdx.x >> 1) * 2 + half;   // per-lane batch
    const int bT = b * T_;

    const float* Whh = dir ? Whh_b : Whh_f;
    const float* bhh = dir ? bhh_b : bhh_f;

    // per-lane weight rows (r=j, z=32+j, n=64+j) as fp32 pairs
    v2f wR[16], wZ[16], wN[16];
    #pragma unroll
    for (int q = 0; q < 16; ++q) {
        wR[q] = *(const v2f*)&Whh[j * 32 + 2 * q];
        wZ[q] = *(const v2f*)&Whh[(32 + j) * 32 + 2 * q];
        wN[q] = *(const v2f*)&Whh[(64 + j) * 32 + 2 * q];
    }
    const float bn = bhh[64 + j];

    const int offR = dir * 96 + j;
    const int offZ = dir * 96 + 32 + j;
    const int offN = dir * 96 + 64 + j;

    // int4 word base for chunk c (fwd: t=4c..4c+3; bwd: t=511-4c..508-4c)
    auto wbase = [&](int c) { return dir ? (bT + 508 - 4 * c) : (bT + 4 * c); };

    // ---- prologue (all loads per-lane: each half tracks its own batch) ----
    int4 ids0 = make_int4(0, 0, 0, 0);
    if (USE_IDS) ids0 = *(const int4*)&ids[wbase(0)];
    int4 mask_use = *(const int4*)&mask[wbase(0)];
    int4 mask_mid = *(const int4*)&mask[wbase(1)];
    int4 mask_in  = make_int4(0, 0, 0, 0);
    int4 ids_pf = make_int4(0, 0, 0, 0), ids_mid = ids_pf, ids_in = ids_pf;
    if (USE_IDS) {
        ids_pf  = *(const int4*)&ids[wbase(1)];
        ids_mid = *(const int4*)&ids[wbase(2)];
    }

    float gR[2][4], gZ[2][4], gN[2][4];
    #pragma unroll
    for (int u = 0; u < 4; ++u) {
        int row;
        if (USE_IDS) {
            const int* ip = (const int*)&ids0;
            row = dir ? ip[3 - u] : ip[u];
        } else {
            row = bT + (dir ? (511 - u) : u);
        }
        const float* gp = gi + (size_t)row * 192;
        gR[0][u] = gp[offR];
        gZ[0][u] = gp[offZ];
        gN[0][u] = gp[offN];
    }

    float h = 0.f;

    for (int c2 = 0; c2 < 64; ++c2) {
        #pragma unroll
        for (int p = 0; p < 2; ++p) {
            const int c = 2 * c2 + p;
            // far prefetch: ids for chunk c+3, mask for chunk c+2 (clamped)
            if (USE_IDS) {
                const int ci = (c + 3 < 128) ? (c + 3) : 127;
                ids_in = *(const int4*)&ids[wbase(ci)];
            }
            {
                const int cm = (c + 2 < 128) ? (c + 2) : 127;
                mask_in = *(const int4*)&mask[wbase(cm)];
            }
            const int cN = (c + 1 < 128) ? (c + 1) : 127;  // gi prefetch chunk

            #pragma unroll
            for (int u = 0; u < 4; ++u) {
                // --- issue gi prefetch for chunk c+1, body u, into bank p^1
                int rowN;
                if (USE_IDS) {
                    const int* ip = (const int*)&ids_pf;
                    rowN = dir ? ip[3 - u] : ip[u];
                } else {
                    rowN = bT + (dir ? (511 - 4 * cN - u) : (4 * cN + u));
                }
                const float* gpN = gi + (size_t)rowN * 192;
                gR[p ^ 1][u] = gpN[offR];
                gZ[p ^ 1][u] = gpN[offZ];
                gN[p ^ 1][u] = gpN[offN];

                // --- compute step (uses bank p, loaded during chunk c-1)
                const int* mu = (const int*)&mask_use;
                const int m = dir ? mu[3 - u] : mu[u];

                // broadcast h within each half via LDS (in-order DS pipe:
                // same-wave RAW needs no barrier; compiler inserts lgkmcnt)
                hsh[l] = h;
                const float* hb = &hsh[half * 32];
                v2f hr[16];
                #pragma unroll
                for (int q = 0; q < 8; ++q) {
                    float4 hv = *(const float4*)&hb[4 * q];
                    hr[2 * q]     = (v2f){hv.x, hv.y};
                    hr[2 * q + 1] = (v2f){hv.z, hv.w};
                }

                v2f aR = {0.f, 0.f}, aZ = {0.f, 0.f}, aN = {0.f, 0.f};
                #pragma unroll
                for (int k = 0; k < 16; ++k) {
                    pk_fma(aR, wR[k], hr[k]);
                    pk_fma(aZ, wZ[k], hr[k]);
                    pk_fma(aN, wN[k], hr[k]);
                }
                const float r  = sigmoidf_fast(gR[p][u] + aR.x + aR.y);
                const float z  = sigmoidf_fast(gZ[p][u] + aZ.x + aZ.y);
                const float hn = bn + aN.x + aN.y;
                const float n  = tanhf_fast(gN[p][u] + r * hn);
                const float hnew = n + z * (h - n);      // (1-z)n + z h
                h = m ? hnew : h;                        // packed-seq freeze

                if (out_seq != nullptr) {
                    const int t = dir ? (511 - 4 * c - u) : (4 * c + u);
                    out_seq[(size_t)(bT + t) * 64 + dir * 32 + j] = h;
                }
            }
            // --- rotate chunk-granular prefetch regs (1-chunk distance)
            mask_use = mask_mid; mask_mid = mask_in;
            if (USE_IDS) { ids_pf = ids_mid; ids_mid = ids_in; }
        }
    }

    if (out_fin != nullptr)
        out_fin[b * 64 + dir * 32 + j] = h;
}

// ---------------------------------------------------------------------------
// Head: out[b,o] = hfin[b,:] . Wout[o,:] + bout[o]
// ---------------------------------------------------------------------------
__global__ void head_kernel(const float* __restrict__ hfin,
                            const float* __restrict__ Wout,
                            const float* __restrict__ bout,
                            float* __restrict__ out)
{
    int idx = blockIdx.x * blockDim.x + threadIdx.x;
    if (idx >= B_ * 6) return;
    int b = idx / 6, o = idx % 6;
    float acc = bout[o];
    const float* hp = hfin + b * 64;
    const float* wp = Wout + o * 64;
    #pragma unroll
    for (int k = 0; k < 64; ++k) acc = fmaf(hp[k], wp[k], acc);
    out[idx] = acc;
}

// ---------------------------------------------------------------------------
extern "C" void kernel_launch(void* const* d_in, const int* in_sizes, int n_in,
                              void* d_out, int out_size, void* d_ws, size_t ws_size,
                              hipStream_t stream)
{
    const int*   ids   = (const int*)d_in[0];
    const int*   mask  = (const int*)d_in[1];
    const float* embed = (const float*)d_in[2];
    const float* Wih0f = (const float*)d_in[3];
    const float* Whh0f = (const float*)d_in[4];
    const float* bih0f = (const float*)d_in[5];
    const float* bhh0f = (const float*)d_in[6];
    const float* Wih0b = (const float*)d_in[7];
    const float* Whh0b = (const float*)d_in[8];
    const float* bih0b = (const float*)d_in[9];
    const float* bhh0b = (const float*)d_in[10];
    const float* Wih1f = (const float*)d_in[11];
    const float* Whh1f = (const float*)d_in[12];
    const float* bih1f = (const float*)d_in[13];
    const float* bhh1f = (const float*)d_in[14];
    const float* Wih1b = (const float*)d_in[15];
    const float* Whh1b = (const float*)d_in[16];
    const float* bih1b = (const float*)d_in[17];
    const float* bhh1b = (const float*)d_in[18];
    const float* Wout  = (const float*)d_in[19];
    const float* bout  = (const float*)d_in[20];

    // workspace layout (floats):
    //   gbuf : G0 [V,192] (K1,K2) then gi1 [B*T,192] (K3,K4)
    //   x1   : [B,T,64]
    //   hfin : [B,64]
    float* ws   = (float*)d_ws;
    float* gbuf = ws;
    float* x1   = ws + (size_t)B_ * T_ * 192;
    float* hfin = x1 + (size_t)B_ * T_ * 64;

    // K1: vocab-factored layer-0 input gates  G0 = embed @ Wcat0^T + bias
    gemm_gates<<<(V_ + GEMM_MT - 1) / GEMM_MT, 256, 0, stream>>>(
        embed, V_, E_, Wih0f, Wih0b, bih0f, bhh0f, bih0b, bhh0b, gbuf);

    // K2: layer-0 bidirectional scan (gathers G0[id]), writes x1
    //     one wave per (batch-pair, direction): 2 * (B/2) blocks
    gru_scan<1><<<B_, 64, 0, stream>>>(
        gbuf, ids, mask, Whh0f, Whh0b, bhh0f, bhh0b, x1, nullptr);

    // K3: layer-1 input gates  gi1 = x1 @ Wcat1^T + bias  (overwrites dead G0)
    gemm_gates<<<(B_ * T_) / GEMM_MT, 256, 0, stream>>>(
        x1, B_ * T_, 64, Wih1f, Wih1b, bih1f, bhh1f, bih1b, bhh1b, gbuf);

    // K4: layer-1 scan, final hiddens only
    gru_scan<0><<<B_, 64, 0, stream>>>(
        gbuf, nullptr, mask, Whh1f, Whh1b, bhh1f, bhh1b, nullptr, hfin);

    // K5: output head
    head_kernel<<<(B_ * 6 + 255) / 256, 256, 0, stream>>>(hfin, Wout, bout,
                                                          (float*)d_out);
}

// Round 2
// 528.394 us; speedup vs baseline: 1.0662x; 1.0028x over previous
//
#include <hip/hip_runtime.h>
#include <hip/hip_bf16.h>
#include <stdint.h>

#define B_ 256
#define T_ 512
#define V_ 30000
#define E_ 256
#define H_ 32

typedef float v2f __attribute__((ext_vector_type(2)));

#define LOG2E_F 1.44269504088896340736f

// ---------------------------------------------------------------------------
// Raw-ISA helpers
// ---------------------------------------------------------------------------
__device__ __forceinline__ float exp2_fast(float x) {      // 2^x
    float r; asm("v_exp_f32 %0, %1" : "=v"(r) : "v"(x)); return r;
}
__device__ __forceinline__ float rcp_fast(float x) {       // 1/x
    float r; asm("v_rcp_f32 %0, %1" : "=v"(r) : "v"(x)); return r;
}
// packed fp32 FMA, all-VGPR operands: acc.{lo,hi} += w.{lo,hi} * h.{lo,hi}
__device__ __forceinline__ void pk_fma(v2f& acc, v2f w, v2f h) {
    asm("v_pk_fma_f32 %0, %1, %2, %0" : "+v"(acc) : "v"(w), "v"(h));
}
// DPP lane-permute move (XOR patterns only -> direction-unambiguous)
template <int CTRL>
__device__ __forceinline__ float mdpp(float x) {
    return __int_as_float(
        __builtin_amdgcn_mov_dpp(__float_as_int(x), CTRL, 0xF, 0xF, true));
}
#define DPP_XOR1  0xB1   // quad_perm [1,0,3,2]
#define DPP_XOR2  0x4E   // quad_perm [2,3,0,1]
#define DPP_XOR3  0x1B   // quad_perm [3,2,1,0]
#define DPP_XOR7  0x141  // row_half_mirror  (i -> i^7 within 8)
#define DPP_XOR15 0x140  // row_mirror       (i -> i^15 within 16)

// ---------------------------------------------------------------------------
// GEMM: Out[M,192] = (A[M,K] @ Wcat[192,K]^T + bias) * gate_scale
// gate_scale folds the exp->exp2 conversion: r,z gates * -log2e ; n * +2log2e
// ---------------------------------------------------------------------------
#define GEMM_MT 64
#define GEMM_KC 32
#define GEMM_PA 68
#define GEMM_PB 196

__global__ __launch_bounds__(256) void gemm_gates(
    const float* __restrict__ A, int M, int K,
    const float* __restrict__ Wf, const float* __restrict__ Wb,
    const float* __restrict__ bihf, const float* __restrict__ bhhf,
    const float* __restrict__ bihb, const float* __restrict__ bhhb,
    float* __restrict__ Out)
{
    __shared__ float As[GEMM_KC][GEMM_PA];
    __shared__ float Bs[GEMM_KC][GEMM_PB];

    const int tid = threadIdx.x;
    const int mbase = blockIdx.x * GEMM_MT;
    const int mg = tid >> 5, ng = tid & 31;
    const int m_off = mg * 8, n_off = ng * 6;

    float acc[8][6];
    #pragma unroll
    for (int r = 0; r < 8; ++r)
        #pragma unroll
        for (int c = 0; c < 6; ++c) acc[r][c] = 0.f;

    for (int kc = 0; kc < K; kc += GEMM_KC) {
        #pragma unroll
        for (int i = 0; i < 2; ++i) {
            int fi = tid + 256 * i;
            int row = fi >> 3, cf = fi & 7;
            int m = mbase + row;
            float4 v = make_float4(0.f, 0.f, 0.f, 0.f);
            if (m < M) v = *(const float4*)&A[(size_t)m * K + kc + cf * 4];
            As[cf * 4 + 0][row] = v.x; As[cf * 4 + 1][row] = v.y;
            As[cf * 4 + 2][row] = v.z; As[cf * 4 + 3][row] = v.w;
        }
        #pragma unroll
        for (int i = 0; i < 6; ++i) {
            int fi = tid + 256 * i;
            int g = fi >> 3, cf = fi & 7;
            const float* Wsel = (g < 96) ? (Wf + (size_t)g * K)
                                         : (Wb + (size_t)(g - 96) * K);
            float4 v = *(const float4*)&Wsel[kc + cf * 4];
            Bs[cf * 4 + 0][g] = v.x; Bs[cf * 4 + 1][g] = v.y;
            Bs[cf * 4 + 2][g] = v.z; Bs[cf * 4 + 3][g] = v.w;
        }
        __syncthreads();
        #pragma unroll
        for (int k = 0; k < GEMM_KC; ++k) {
            float a[8], bb[6];
            *(float4*)&a[0] = *(const float4*)&As[k][m_off];
            *(float4*)&a[4] = *(const float4*)&As[k][m_off + 4];
            *(float2*)&bb[0] = *(const float2*)&Bs[k][n_off];
            *(float2*)&bb[2] = *(const float2*)&Bs[k][n_off + 2];
            *(float2*)&bb[4] = *(const float2*)&Bs[k][n_off + 4];
            #pragma unroll
            for (int r = 0; r < 8; ++r)
                #pragma unroll
                for (int c = 0; c < 6; ++c)
                    acc[r][c] = fmaf(a[r], bb[c], acc[r][c]);
        }
        __syncthreads();
    }

    float bias[6], gsc[6];
    #pragma unroll
    for (int c = 0; c < 6; ++c) {
        int g = n_off + c;
        int g96 = (g < 96) ? g : g - 96;
        const float* bih = (g < 96) ? bihf : bihb;
        const float* bhh = (g < 96) ? bhhf : bhhb;
        bias[c] = bih[g96] + ((g96 < 64) ? bhh[g96] : 0.f);
        gsc[c]  = (g96 < 64) ? -LOG2E_F : 2.0f * LOG2E_F;
    }
    #pragma unroll
    for (int r = 0; r < 8; ++r) {
        int m = mbase + m_off + r;
        if (m < M) {
            float* op = &Out[(size_t)m * 192 + n_off];
            #pragma unroll
            for (int c = 0; c < 6; ++c) op[c] = (acc[r][c] + bias[c]) * gsc[c];
        }
    }
}

// ---------------------------------------------------------------------------
// GRU scan. One wave per (batch, direction); unit j = l&31, redundant halves.
// Per-step h broadcast is SPLIT:
//   - own 16-row's k-half (row r holds h[16*(r&1)..+15]) via a 15-instruction
//     DPP XOR-butterfly all-gather (VALU pipe, ~50cy, per-lane k-order
//     absorbed into pre-permuted weight registers)
//   - other k-half via LDS broadcast ds_read_b128 x4; the ds_write->ds_read
//     RAW (~150cy, in-order DS pipe) is issued at step top and consumed only
//     AFTER the DPP-half matvec -> latency hidden under real work.
// Matvec: 48 v_pk_fma_f32 split into depth-8 (A, hidden) + 2x depth-4 (B)
// accumulator chains. Activations use exp2/rcp with log2e pre-folded into
// all gate pre-activations (GEMM epilogue + scaled Whh/bhh).
// gi prefetch: 128 chunks of 4 steps, two register banks alternate per chunk.
// ---------------------------------------------------------------------------
template <int USE_IDS>
__global__ __launch_bounds__(64, 1) void gru_scan(
    const float* __restrict__ gi,     // [rows,192]: G0 (gather) or gi1 (direct)
    const int* __restrict__ ids,
    const int* __restrict__ mask,
    const float* __restrict__ Whh_f, const float* __restrict__ Whh_b,
    const float* __restrict__ bhh_f, const float* __restrict__ bhh_b,
    float* __restrict__ out_seq,      // [B,T,64] or nullptr
    float* __restrict__ out_fin)      // [B,64]   or nullptr
{
    __shared__ float hsh[64];

    const int l = threadIdx.x;
    const int i16 = l & 15;
    const int rp = (l >> 4) & 1;      // row parity: which k-half this row holds
    const int j = l & 31;             // unit
    const bool lower = l < 32;
    const int dir = blockIdx.x & 1;
    const int b = blockIdx.x >> 1;
    const int bT = b * T_;

    const float* Whh = dir ? Whh_b : Whh_f;
    const float* bhh = dir ? bhh_b : bhh_f;

    const int kA = 16 * rp;           // own half (DPP gather)
    const int kB = 16 - kA;           // other half (LDS)

    const float sRZ = -LOG2E_F;
    const float sN2 = 2.0f * LOG2E_F;

    // XOR-offset tables: DPP gather pair q holds h[kA + (i16^M0[q])],
    // h[kA + (i16^M1[q])] — weights loaded in matching per-lane order.
    const int M0[8] = {0, 2, 7, 5, 15, 13, 8, 10};
    const int M1[8] = {1, 3, 6, 4, 14, 12, 9, 11};

    v2f wAR[8], wAZ[8], wAN[8], wBR[8], wBZ[8], wBN[8];
    #pragma unroll
    for (int q = 0; q < 8; ++q) {
        const int ka0 = kA + (i16 ^ M0[q]);
        const int ka1 = kA + (i16 ^ M1[q]);
        wAR[q] = (v2f){Whh[j * 32 + ka0] * sRZ, Whh[j * 32 + ka1] * sRZ};
        wAZ[q] = (v2f){Whh[(32 + j) * 32 + ka0] * sRZ,
                       Whh[(32 + j) * 32 + ka1] * sRZ};
        wAN[q] = (v2f){Whh[(64 + j) * 32 + ka0] * sN2,
                       Whh[(64 + j) * 32 + ka1] * sN2};
        v2f br = *(const v2f*)&Whh[j * 32 + kB + 2 * q];
        v2f bz = *(const v2f*)&Whh[(32 + j) * 32 + kB + 2 * q];
        v2f bn_ = *(const v2f*)&Whh[(64 + j) * 32 + kB + 2 * q];
        wBR[q] = (v2f){br.x * sRZ, br.y * sRZ};
        wBZ[q] = (v2f){bz.x * sRZ, bz.y * sRZ};
        wBN[q] = (v2f){bn_.x * sN2, bn_.y * sN2};
    }
    const float bns = bhh[64 + j] * sN2;

    const int offR = dir * 96 + j;
    const int offZ = dir * 96 + 32 + j;
    const int offN = dir * 96 + 64 + j;

    // int4 word base for chunk c (fwd: t=4c..4c+3; bwd: t=511-4c..508-4c)
    auto wbase = [&](int c) { return dir ? (bT + 508 - 4 * c) : (bT + 4 * c); };

    // ---- prologue ----
    int4 ids0 = make_int4(0, 0, 0, 0);
    if (USE_IDS) ids0 = *(const int4*)&ids[wbase(0)];
    int4 mask_use = *(const int4*)&mask[wbase(0)];
    int4 mask_mid = *(const int4*)&mask[wbase(1)];
    int4 mask_in  = make_int4(0, 0, 0, 0);
    int4 ids_pf = make_int4(0, 0, 0, 0), ids_mid = ids_pf, ids_in = ids_pf;
    if (USE_IDS) {
        ids_pf  = *(const int4*)&ids[wbase(1)];
        ids_mid = *(const int4*)&ids[wbase(2)];
    }

    float gR[2][4], gZ[2][4], gN[2][4];
    #pragma unroll
    for (int u = 0; u < 4; ++u) {
        int row;
        if (USE_IDS) {
            const int* ip = (const int*)&ids0;
            row = dir ? ip[3 - u] : ip[u];
        } else {
            row = bT + (dir ? (511 - u) : u);
        }
        const float* gp = gi + (size_t)row * 192;
        gR[0][u] = gp[offR];
        gZ[0][u] = gp[offZ];
        gN[0][u] = gp[offN];
    }

    float h = 0.f;
    hsh[l] = 0.f;   // seed LDS copy of h (same-wave DS, in-order pipe)

    for (int c2 = 0; c2 < 64; ++c2) {
        #pragma unroll
        for (int pb = 0; pb < 2; ++pb) {
            const int c = 2 * c2 + pb;
            // far prefetch: ids for chunk c+3, mask for chunk c+2 (clamped)
            if (USE_IDS) {
                const int ci = (c + 3 < 128) ? (c + 3) : 127;
                ids_in = *(const int4*)&ids[wbase(ci)];
            }
            {
                const int cm = (c + 2 < 128) ? (c + 2) : 127;
                mask_in = *(const int4*)&mask[wbase(cm)];
            }
            const int cN = (c + 1 < 128) ? (c + 1) : 127;  // gi prefetch chunk

            #pragma unroll
            for (int u = 0; u < 4; ++u) {
                // --- issue gi prefetch for chunk c+1, body u, into bank pb^1
                int rowN;
                if (USE_IDS) {
                    const int* ip = (const int*)&ids_pf;
                    rowN = dir ? ip[3 - u] : ip[u];
                } else {
                    rowN = bT + (dir ? (511 - 4 * cN - u) : (4 * cN + u));
                }
                const float* gpN = gi + (size_t)rowN * 192;
                gR[pb ^ 1][u] = gpN[offR];
                gZ[pb ^ 1][u] = gpN[offZ];
                gN[pb ^ 1][u] = gpN[offN];

                // --- compute step (gi bank pb, loaded during chunk c-1)
                const int* mu = (const int*)&mask_use;
                const int m = dir ? mu[3 - u] : mu[u];

                // other-half h via LDS (RAW on previous step's ds_write;
                // consumed only after matvec-A -> latency hidden)
                float4 o0 = *(const float4*)&hsh[kB + 0];
                float4 o1 = *(const float4*)&hsh[kB + 4];
                float4 o2 = *(const float4*)&hsh[kB + 8];
                float4 o3 = *(const float4*)&hsh[kB + 12];

                // own-half h via DPP XOR-butterfly all-gather (depth 3)
                v2f p[8];
                p[0].x = h;                      p[0].y = mdpp<DPP_XOR1>(h);
                p[1].x = mdpp<DPP_XOR2>(h);      p[1].y = mdpp<DPP_XOR3>(h);
                p[2].x = mdpp<DPP_XOR7>(h);      p[2].y = mdpp<DPP_XOR7>(p[0].y);
                p[3].x = mdpp<DPP_XOR7>(p[1].x); p[3].y = mdpp<DPP_XOR7>(p[1].y);
                p[4].x = mdpp<DPP_XOR15>(h);     p[4].y = mdpp<DPP_XOR15>(p[0].y);
                p[5].x = mdpp<DPP_XOR15>(p[1].x); p[5].y = mdpp<DPP_XOR15>(p[1].y);
                p[6].x = mdpp<DPP_XOR15>(p[2].x); p[6].y = mdpp<DPP_XOR15>(p[2].y);
                p[7].x = mdpp<DPP_XOR15>(p[3].x); p[7].y = mdpp<DPP_XOR15>(p[3].y);

                v2f aAR = {0.f, 0.f}, aAZ = {0.f, 0.f}, aAN = {0.f, 0.f};
                #pragma unroll
                for (int q = 0; q < 8; ++q) {
                    pk_fma(aAR, wAR[q], p[q]);
                    pk_fma(aAZ, wAZ[q], p[q]);
                    pk_fma(aAN, wAN[q], p[q]);
                }

                v2f hB[8];
                hB[0] = (v2f){o0.x, o0.y}; hB[1] = (v2f){o0.z, o0.w};
                hB[2] = (v2f){o1.x, o1.y}; hB[3] = (v2f){o1.z, o1.w};
                hB[4] = (v2f){o2.x, o2.y}; hB[5] = (v2f){o2.z, o2.w};
                hB[6] = (v2f){o3.x, o3.y}; hB[7] = (v2f){o3.z, o3.w};

                v2f aB0R = {0.f, 0.f}, aB0Z = {0.f, 0.f}, aB0N = {0.f, 0.f};
                v2f aB1R = {0.f, 0.f}, aB1Z = {0.f, 0.f}, aB1N = {0.f, 0.f};
                #pragma unroll
                for (int q = 0; q < 4; ++q) {
                    pk_fma(aB0R, wBR[q], hB[q]);
                    pk_fma(aB0Z, wBZ[q], hB[q]);
                    pk_fma(aB0N, wBN[q], hB[q]);
                }
                #pragma unroll
                for (int q = 4; q < 8; ++q) {
                    pk_fma(aB1R, wBR[q], hB[q]);
                    pk_fma(aB1Z, wBZ[q], hB[q]);
                    pk_fma(aB1N, wBN[q], hB[q]);
                }

                const float yr = (gR[pb][u] + (aAR.x + aAR.y)) +
                                 ((aB0R.x + aB0R.y) + (aB1R.x + aB1R.y));
                const float yz = (gZ[pb][u] + (aAZ.x + aAZ.y)) +
                                 ((aB0Z.x + aB0Z.y) + (aB1Z.x + aB1Z.y));
                const float hns = (bns + (aAN.x + aAN.y)) +
                                  ((aB0N.x + aB0N.y) + (aB1N.x + aB1N.y));
                const float r = rcp_fast(1.0f + exp2_fast(yr));
                const float z = rcp_fast(1.0f + exp2_fast(yz));
                const float yn = gN[pb][u] + r * hns;
                const float n = fmaf(-2.0f, rcp_fast(1.0f + exp2_fast(yn)), 1.0f);
                const float hnew = n + z * (h - n);      // (1-z)n + z h
                h = m ? hnew : h;                        // packed-seq freeze

                hsh[l] = h;   // feeds next step's other-half LDS reads

                if (out_seq != nullptr) {
                    const int t = dir ? (511 - 4 * c - u) : (4 * c + u);
                    if (lower)
                        out_seq[(size_t)(bT + t) * 64 + dir * 32 + j] = h;
                }
            }
            // --- rotate chunk-granular prefetch regs (1-chunk distance)
            mask_use = mask_mid; mask_mid = mask_in;
            if (USE_IDS) { ids_pf = ids_mid; ids_mid = ids_in; }
        }
    }

    if (out_fin != nullptr && lower)
        out_fin[b * 64 + dir * 32 + j] = h;
}

// ---------------------------------------------------------------------------
// Head: out[b,o] = hfin[b,:] . Wout[o,:] + bout[o]
// ---------------------------------------------------------------------------
__global__ void head_kernel(const float* __restrict__ hfin,
                            const float* __restrict__ Wout,
                            const float* __restrict__ bout,
                            float* __restrict__ out)
{
    int idx = blockIdx.x * blockDim.x + threadIdx.x;
    if (idx >= B_ * 6) return;
    int b = idx / 6, o = idx % 6;
    float acc = bout[o];
    const float* hp = hfin + b * 64;
    const float* wp = Wout + o * 64;
    #pragma unroll
    for (int k = 0; k < 64; ++k) acc = fmaf(hp[k], wp[k], acc);
    out[idx] = acc;
}

// ---------------------------------------------------------------------------
extern "C" void kernel_launch(void* const* d_in, const int* in_sizes, int n_in,
                              void* d_out, int out_size, void* d_ws, size_t ws_size,
                              hipStream_t stream)
{
    const int*   ids   = (const int*)d_in[0];
    const int*   mask  = (const int*)d_in[1];
    const float* embed = (const float*)d_in[2];
    const float* Wih0f = (const float*)d_in[3];
    const float* Whh0f = (const float*)d_in[4];
    const float* bih0f = (const float*)d_in[5];
    const float* bhh0f = (const float*)d_in[6];
    const float* Wih0b = (const float*)d_in[7];
    const float* Whh0b = (const float*)d_in[8];
    const float* bih0b = (const float*)d_in[9];
    const float* bhh0b = (const float*)d_in[10];
    const float* Wih1f = (const float*)d_in[11];
    const float* Whh1f = (const float*)d_in[12];
    const float* bih1f = (const float*)d_in[13];
    const float* bhh1f = (const float*)d_in[14];
    const float* Wih1b = (const float*)d_in[15];
    const float* Whh1b = (const float*)d_in[16];
    const float* bih1b = (const float*)d_in[17];
    const float* bhh1b = (const float*)d_in[18];
    const float* Wout  = (const float*)d_in[19];
    const float* bout  = (const float*)d_in[20];

    // workspace layout (floats):
    //   gbuf : G0 [V,192] (K1,K2) then gi1 [B*T,192] (K3,K4)
    //   x1   : [B,T,64]
    //   hfin : [B,64]
    float* ws   = (float*)d_ws;
    float* gbuf = ws;
    float* x1   = ws + (size_t)B_ * T_ * 192;
    float* hfin = x1 + (size_t)B_ * T_ * 64;

    // K1: vocab-factored layer-0 input gates  G0 = (embed @ Wcat0^T + b) * gsc
    gemm_gates<<<(V_ + GEMM_MT - 1) / GEMM_MT, 256, 0, stream>>>(
        embed, V_, E_, Wih0f, Wih0b, bih0f, bhh0f, bih0b, bhh0b, gbuf);

    // K2: layer-0 bidirectional scan (gathers G0[id]), writes x1
    gru_scan<1><<<2 * B_, 64, 0, stream>>>(
        gbuf, ids, mask, Whh0f, Whh0b, bhh0f, bhh0b, x1, nullptr);

    // K3: layer-1 input gates  gi1 = (x1 @ Wcat1^T + b) * gsc
    gemm_gates<<<(B_ * T_) / GEMM_MT, 256, 0, stream>>>(
        x1, B_ * T_, 64, Wih1f, Wih1b, bih1f, bhh1f, bih1b, bhh1b, gbuf);

    // K4: layer-1 scan, final hiddens only
    gru_scan<0><<<2 * B_, 64, 0, stream>>>(
        gbuf, nullptr, mask, Whh1f, Whh1b, bhh1f, bhh1b, nullptr, hfin);

    // K5: output head
    head_kernel<<<(B_ * 6 + 255) / 256, 256, 0, stream>>>(hfin, Wout, bout,
                                                          (float*)d_out);
}

// Round 3
// 525.379 us; speedup vs baseline: 1.0723x; 1.0057x over previous
//
#include <hip/hip_runtime.h>
#include <hip/hip_bf16.h>
#include <stdint.h>

#define B_ 256
#define T_ 512
#define V_ 30000
#define E_ 256
#define H_ 32

typedef float v2f __attribute__((ext_vector_type(2)));
typedef unsigned int uint2e __attribute__((ext_vector_type(2)));

#define LOG2E_F 1.44269504088896340736f

// ---------------------------------------------------------------------------
// Raw-ISA helpers
// ---------------------------------------------------------------------------
__device__ __forceinline__ float exp2_fast(float x) {      // 2^x
    float r; asm("v_exp_f32 %0, %1" : "=v"(r) : "v"(x)); return r;
}
__device__ __forceinline__ float rcp_fast(float x) {       // 1/x
    float r; asm("v_rcp_f32 %0, %1" : "=v"(r) : "v"(x)); return r;
}
// packed fp32 FMA, all-VGPR operands: acc.{lo,hi} += w.{lo,hi} * h.{lo,hi}
__device__ __forceinline__ void pk_fma(v2f& acc, v2f w, v2f h) {
    asm("v_pk_fma_f32 %0, %1, %2, %0" : "+v"(acc) : "v"(w), "v"(h));
}
// DPP lane-permute move (XOR patterns only -> direction-unambiguous)
template <int CTRL>
__device__ __forceinline__ float mdpp(float x) {
    return __int_as_float(
        __builtin_amdgcn_mov_dpp(__float_as_int(x), CTRL, 0xF, 0xF, true));
}
#define DPP_XOR1  0xB1   // quad_perm [1,0,3,2]
#define DPP_XOR2  0x4E   // quad_perm [2,3,0,1]
#define DPP_XOR3  0x1B   // quad_perm [3,2,1,0]
#define DPP_XOR7  0x141  // row_half_mirror  (i -> i^7 within 8)
#define DPP_XOR15 0x140  // row_mirror       (i -> i^15 within 16)

// cross-32 half swap: returns value of h from lane (l ^ 32). VALU pipe.
// {r.x, r.y} per lane is {original, swapped} in hw-defined order -> xor-fold
// makes the selection convention-independent.
__device__ __forceinline__ float swap32(float h) {
    uint2e r = __builtin_amdgcn_permlane32_swap(
        __float_as_uint(h), __float_as_uint(h), false, false);
    return __uint_as_float(r.x ^ r.y ^ __float_as_uint(h));
}

// ---------------------------------------------------------------------------
// GEMM: Out[M,192] = (A[M,K] @ Wcat[192,K]^T + bias) * gate_scale
// gate_scale folds the exp->exp2 conversion: r,z gates * -log2e ; n * +2log2e
// ---------------------------------------------------------------------------
#define GEMM_MT 64
#define GEMM_KC 32
#define GEMM_PA 68
#define GEMM_PB 196

__global__ __launch_bounds__(256) void gemm_gates(
    const float* __restrict__ A, int M, int K,
    const float* __restrict__ Wf, const float* __restrict__ Wb,
    const float* __restrict__ bihf, const float* __restrict__ bhhf,
    const float* __restrict__ bihb, const float* __restrict__ bhhb,
    float* __restrict__ Out)
{
    __shared__ float As[GEMM_KC][GEMM_PA];
    __shared__ float Bs[GEMM_KC][GEMM_PB];

    const int tid = threadIdx.x;
    const int mbase = blockIdx.x * GEMM_MT;
    const int mg = tid >> 5, ng = tid & 31;
    const int m_off = mg * 8, n_off = ng * 6;

    float acc[8][6];
    #pragma unroll
    for (int r = 0; r < 8; ++r)
        #pragma unroll
        for (int c = 0; c < 6; ++c) acc[r][c] = 0.f;

    for (int kc = 0; kc < K; kc += GEMM_KC) {
        #pragma unroll
        for (int i = 0; i < 2; ++i) {
            int fi = tid + 256 * i;
            int row = fi >> 3, cf = fi & 7;
            int m = mbase + row;
            float4 v = make_float4(0.f, 0.f, 0.f, 0.f);
            if (m < M) v = *(const float4*)&A[(size_t)m * K + kc + cf * 4];
            As[cf * 4 + 0][row] = v.x; As[cf * 4 + 1][row] = v.y;
            As[cf * 4 + 2][row] = v.z; As[cf * 4 + 3][row] = v.w;
        }
        #pragma unroll
        for (int i = 0; i < 6; ++i) {
            int fi = tid + 256 * i;
            int g = fi >> 3, cf = fi & 7;
            const float* Wsel = (g < 96) ? (Wf + (size_t)g * K)
                                         : (Wb + (size_t)(g - 96) * K);
            float4 v = *(const float4*)&Wsel[kc + cf * 4];
            Bs[cf * 4 + 0][g] = v.x; Bs[cf * 4 + 1][g] = v.y;
            Bs[cf * 4 + 2][g] = v.z; Bs[cf * 4 + 3][g] = v.w;
        }
        __syncthreads();
        #pragma unroll
        for (int k = 0; k < GEMM_KC; ++k) {
            float a[8], bb[6];
            *(float4*)&a[0] = *(const float4*)&As[k][m_off];
            *(float4*)&a[4] = *(const float4*)&As[k][m_off + 4];
            *(float2*)&bb[0] = *(const float2*)&Bs[k][n_off];
            *(float2*)&bb[2] = *(const float2*)&Bs[k][n_off + 2];
            *(float2*)&bb[4] = *(const float2*)&Bs[k][n_off + 4];
            #pragma unroll
            for (int r = 0; r < 8; ++r)
                #pragma unroll
                for (int c = 0; c < 6; ++c)
                    acc[r][c] = fmaf(a[r], bb[c], acc[r][c]);
        }
        __syncthreads();
    }

    float bias[6], gsc[6];
    #pragma unroll
    for (int c = 0; c < 6; ++c) {
        int g = n_off + c;
        int g96 = (g < 96) ? g : g - 96;
        const float* bih = (g < 96) ? bihf : bihb;
        const float* bhh = (g < 96) ? bhhf : bhhb;
        bias[c] = bih[g96] + ((g96 < 64) ? bhh[g96] : 0.f);
        gsc[c]  = (g96 < 64) ? -LOG2E_F : 2.0f * LOG2E_F;
    }
    #pragma unroll
    for (int r = 0; r < 8; ++r) {
        int m = mbase + m_off + r;
        if (m < M) {
            float* op = &Out[(size_t)m * 192 + n_off];
            #pragma unroll
            for (int c = 0; c < 6; ++c) op[c] = (acc[r][c] + bias[c]) * gsc[c];
        }
    }
}

// ---------------------------------------------------------------------------
// GRU scan. One wave per (batch, direction). Row layout (16-lane rows hold
// units L,H,H,L): row r holds h-units 16*hi(r)..+15 with hi = r in {1,2}.
// Per-step h broadcast is ALL-VALU:
//   - one v_permlane32_swap_b32 gives every lane its complement-half seed
//     (rows 0<->2, 1<->3 are exactly the complement rows in this layout)
//   - a 15-op DPP XOR-butterfly on each seed distributes all 16 values of
//     each half; per-lane value order (i16 ^ M[q]) is absorbed into
//     per-lane permuted weight registers at init.
// Weights are PINNED in VGPRs via opaque asm (the compiler was observed
// rematerializing the 96 weight regs from memory every step: VGPR_Count=84
// with >=150 live values declared -> ~48 reloads/step was the real stall).
// Matvec: 48 v_pk_fma_f32 in 6 independent depth-8 chains. Activations:
// exp2/rcp with log2e pre-folded into all gate pre-activations.
// gi prefetch: 128 chunks of 4 steps, two register banks alternate per chunk.
// ---------------------------------------------------------------------------
template <int USE_IDS>
__global__ __launch_bounds__(64, 1) void gru_scan(
    const float* __restrict__ gi,     // [rows,192]: G0 (gather) or gi1 (direct)
    const int* __restrict__ ids,
    const int* __restrict__ mask,
    const float* __restrict__ Whh_f, const float* __restrict__ Whh_b,
    const float* __restrict__ bhh_f, const float* __restrict__ bhh_b,
    float* __restrict__ out_seq,      // [B,T,64] or nullptr
    float* __restrict__ out_fin)      // [B,64]   or nullptr
{
    const int l = threadIdx.x;
    const int i16 = l & 15;
    const int row = l >> 4;
    const int hi = (row ^ (row >> 1)) & 1;   // rows 1,2 -> high units
    const int j = i16 + 16 * hi;             // this lane's unit
    const bool lower = l < 32;               // lanes 0-31: j == l&31
    const int dir = blockIdx.x & 1;
    const int b = blockIdx.x >> 1;
    const int bT = b * T_;

    const float* Whh = dir ? Whh_b : Whh_f;
    const float* bhh = dir ? bhh_b : bhh_f;

    const int kA = 16 * hi;          // own half (butterfly on h)
    const int kB = 16 - kA;          // complement half (butterfly on swap32(h))

    const float sRZ = -LOG2E_F;
    const float sN2 = 2.0f * LOG2E_F;

    // butterfly value order: pair q holds h[base + (i16^M0[q])], h[base+(i16^M1[q])]
    const int M0[8] = {0, 2, 7, 5, 15, 13, 8, 10};
    const int M1[8] = {1, 3, 6, 4, 14, 12, 9, 11};

    v2f wAR[8], wAZ[8], wAN[8], wBR[8], wBZ[8], wBN[8];
    #pragma unroll
    for (int q = 0; q < 8; ++q) {
        const int a0 = kA + (i16 ^ M0[q]);
        const int a1 = kA + (i16 ^ M1[q]);
        const int b0 = kB + (i16 ^ M0[q]);
        const int b1 = kB + (i16 ^ M1[q]);
        wAR[q] = (v2f){Whh[j * 32 + a0] * sRZ, Whh[j * 32 + a1] * sRZ};
        wAZ[q] = (v2f){Whh[(32 + j) * 32 + a0] * sRZ, Whh[(32 + j) * 32 + a1] * sRZ};
        wAN[q] = (v2f){Whh[(64 + j) * 32 + a0] * sN2, Whh[(64 + j) * 32 + a1] * sN2};
        wBR[q] = (v2f){Whh[j * 32 + b0] * sRZ, Whh[j * 32 + b1] * sRZ};
        wBZ[q] = (v2f){Whh[(32 + j) * 32 + b0] * sRZ, Whh[(32 + j) * 32 + b1] * sRZ};
        wBN[q] = (v2f){Whh[(64 + j) * 32 + b0] * sN2, Whh[(64 + j) * 32 + b1] * sN2};
    }
    float bns = bhh[64 + j] * sN2;

    // PIN: make weight values opaque so the allocator cannot sink the loads
    // into the scan loop (forces true VGPR residency for all 96 weight regs).
    #pragma unroll
    for (int q = 0; q < 8; ++q) {
        asm volatile("" : "+v"(wAR[q]), "+v"(wAZ[q]), "+v"(wAN[q]),
                          "+v"(wBR[q]), "+v"(wBZ[q]), "+v"(wBN[q]));
    }
    asm volatile("" : "+v"(bns));

    const int offR = dir * 96 + j;
    const int offZ = dir * 96 + 32 + j;
    const int offN = dir * 96 + 64 + j;

    // int4 word base for chunk c (fwd: t=4c..4c+3; bwd: t=511-4c..508-4c)
    auto wbase = [&](int c) { return dir ? (bT + 508 - 4 * c) : (bT + 4 * c); };

    // ---- prologue ----
    int4 ids0 = make_int4(0, 0, 0, 0);
    if (USE_IDS) ids0 = *(const int4*)&ids[wbase(0)];
    int4 mask_use = *(const int4*)&mask[wbase(0)];
    int4 mask_mid = *(const int4*)&mask[wbase(1)];
    int4 mask_in  = make_int4(0, 0, 0, 0);
    int4 ids_pf = make_int4(0, 0, 0, 0), ids_mid = ids_pf, ids_in = ids_pf;
    if (USE_IDS) {
        ids_pf  = *(const int4*)&ids[wbase(1)];
        ids_mid = *(const int4*)&ids[wbase(2)];
    }

    float gR[2][4], gZ[2][4], gN[2][4];
    #pragma unroll
    for (int u = 0; u < 4; ++u) {
        int rowi;
        if (USE_IDS) {
            const int* ip = (const int*)&ids0;
            rowi = dir ? ip[3 - u] : ip[u];
        } else {
            rowi = bT + (dir ? (511 - u) : u);
        }
        const float* gp = gi + (size_t)rowi * 192;
        gR[0][u] = gp[offR];
        gZ[0][u] = gp[offZ];
        gN[0][u] = gp[offN];
    }

    float h = 0.f;

    for (int c2 = 0; c2 < 64; ++c2) {
        #pragma unroll
        for (int pb = 0; pb < 2; ++pb) {
            const int c = 2 * c2 + pb;
            // far prefetch: ids for chunk c+3, mask for chunk c+2 (clamped)
            if (USE_IDS) {
                const int ci = (c + 3 < 128) ? (c + 3) : 127;
                ids_in = *(const int4*)&ids[wbase(ci)];
            }
            {
                const int cm = (c + 2 < 128) ? (c + 2) : 127;
                mask_in = *(const int4*)&mask[wbase(cm)];
            }
            const int cN = (c + 1 < 128) ? (c + 1) : 127;  // gi prefetch chunk

            #pragma unroll
            for (int u = 0; u < 4; ++u) {
                // --- issue gi prefetch for chunk c+1, body u, into bank pb^1
                int rowN;
                if (USE_IDS) {
                    const int* ip = (const int*)&ids_pf;
                    rowN = dir ? ip[3 - u] : ip[u];
                } else {
                    rowN = bT + (dir ? (511 - 4 * cN - u) : (4 * cN + u));
                }
                const float* gpN = gi + (size_t)rowN * 192;
                gR[pb ^ 1][u] = gpN[offR];
                gZ[pb ^ 1][u] = gpN[offZ];
                gN[pb ^ 1][u] = gpN[offN];

                // --- compute step (gi bank pb, loaded during chunk c-1)
                const int* mu = (const int*)&mask_use;
                const int m = dir ? mu[3 - u] : mu[u];

                // h broadcast, all-VALU: complement seed via permlane swap,
                // then a 15-op DPP XOR-butterfly on each seed.
                const float hs = swap32(h);

                v2f p[8], p2[8];
                {
                    p[0].x = h;                       p[0].y = mdpp<DPP_XOR1>(h);
                    p[1].x = mdpp<DPP_XOR2>(h);       p[1].y = mdpp<DPP_XOR3>(h);
                    p[2].x = mdpp<DPP_XOR7>(h);       p[2].y = mdpp<DPP_XOR7>(p[0].y);
                    p[3].x = mdpp<DPP_XOR7>(p[1].x);  p[3].y = mdpp<DPP_XOR7>(p[1].y);
                    p[4].x = mdpp<DPP_XOR15>(h);      p[4].y = mdpp<DPP_XOR15>(p[0].y);
                    p[5].x = mdpp<DPP_XOR15>(p[1].x); p[5].y = mdpp<DPP_XOR15>(p[1].y);
                    p[6].x = mdpp<DPP_XOR15>(p[2].x); p[6].y = mdpp<DPP_XOR15>(p[2].y);
                    p[7].x = mdpp<DPP_XOR15>(p[3].x); p[7].y = mdpp<DPP_XOR15>(p[3].y);

                    p2[0].x = hs;                       p2[0].y = mdpp<DPP_XOR1>(hs);
                    p2[1].x = mdpp<DPP_XOR2>(hs);       p2[1].y = mdpp<DPP_XOR3>(hs);
                    p2[2].x = mdpp<DPP_XOR7>(hs);       p2[2].y = mdpp<DPP_XOR7>(p2[0].y);
                    p2[3].x = mdpp<DPP_XOR7>(p2[1].x);  p2[3].y = mdpp<DPP_XOR7>(p2[1].y);
                    p2[4].x = mdpp<DPP_XOR15>(hs);      p2[4].y = mdpp<DPP_XOR15>(p2[0].y);
                    p2[5].x = mdpp<DPP_XOR15>(p2[1].x); p2[5].y = mdpp<DPP_XOR15>(p2[1].y);
                    p2[6].x = mdpp<DPP_XOR15>(p2[2].x); p2[6].y = mdpp<DPP_XOR15>(p2[2].y);
                    p2[7].x = mdpp<DPP_XOR15>(p2[3].x); p2[7].y = mdpp<DPP_XOR15>(p2[3].y);
                }

                // matvec: 6 independent depth-8 pk_fma chains
                v2f aR0 = {0.f, 0.f}, aZ0 = {0.f, 0.f}, aN0 = {0.f, 0.f};
                v2f aR1 = {0.f, 0.f}, aZ1 = {0.f, 0.f}, aN1 = {0.f, 0.f};
                #pragma unroll
                for (int q = 0; q < 8; ++q) {
                    pk_fma(aR0, wAR[q], p[q]);
                    pk_fma(aZ0, wAZ[q], p[q]);
                    pk_fma(aN0, wAN[q], p[q]);
                    pk_fma(aR1, wBR[q], p2[q]);
                    pk_fma(aZ1, wBZ[q], p2[q]);
                    pk_fma(aN1, wBN[q], p2[q]);
                }
                const v2f sR = aR0 + aR1;
                const v2f sZ = aZ0 + aZ1;
                const v2f sN = aN0 + aN1;

                const float yr  = (gR[pb][u] + sR.x) + sR.y;
                const float yz  = (gZ[pb][u] + sZ.x) + sZ.y;
                const float hns = (bns + sN.x) + sN.y;
                const float r = rcp_fast(1.0f + exp2_fast(yr));
                const float z = rcp_fast(1.0f + exp2_fast(yz));
                const float yn = gN[pb][u] + r * hns;
                const float n = fmaf(-2.0f, rcp_fast(1.0f + exp2_fast(yn)), 1.0f);
                const float hnew = n + z * (h - n);      // (1-z)n + z h
                h = m ? hnew : h;                        // packed-seq freeze

                if (out_seq != nullptr) {
                    const int t = dir ? (511 - 4 * c - u) : (4 * c + u);
                    if (lower)
                        out_seq[(size_t)(bT + t) * 64 + dir * 32 + j] = h;
                }
            }
            // --- rotate chunk-granular prefetch regs (1-chunk distance)
            mask_use = mask_mid; mask_mid = mask_in;
            if (USE_IDS) { ids_pf = ids_mid; ids_mid = ids_in; }
        }
    }

    if (out_fin != nullptr && lower)
        out_fin[b * 64 + dir * 32 + j] = h;
}

// ---------------------------------------------------------------------------
// Head: out[b,o] = hfin[b,:] . Wout[o,:] + bout[o]
// ---------------------------------------------------------------------------
__global__ void head_kernel(const float* __restrict__ hfin,
                            const float* __restrict__ Wout,
                            const float* __restrict__ bout,
                            float* __restrict__ out)
{
    int idx = blockIdx.x * blockDim.x + threadIdx.x;
    if (idx >= B_ * 6) return;
    int b = idx / 6, o = idx % 6;
    float acc = bout[o];
    const float* hp = hfin + b * 64;
    const float* wp = Wout + o * 64;
    #pragma unroll
    for (int k = 0; k < 64; ++k) acc = fmaf(hp[k], wp[k], acc);
    out[idx] = acc;
}

// ---------------------------------------------------------------------------
extern "C" void kernel_launch(void* const* d_in, const int* in_sizes, int n_in,
                              void* d_out, int out_size, void* d_ws, size_t ws_size,
                              hipStream_t stream)
{
    const int*   ids   = (const int*)d_in[0];
    const int*   mask  = (const int*)d_in[1];
    const float* embed = (const float*)d_in[2];
    const float* Wih0f = (const float*)d_in[3];
    const float* Whh0f = (const float*)d_in[4];
    const float* bih0f = (const float*)d_in[5];
    const float* bhh0f = (const float*)d_in[6];
    const float* Wih0b = (const float*)d_in[7];
    const float* Whh0b = (const float*)d_in[8];
    const float* bih0b = (const float*)d_in[9];
    const float* bhh0b = (const float*)d_in[10];
    const float* Wih1f = (const float*)d_in[11];
    const float* Whh1f = (const float*)d_in[12];
    const float* bih1f = (const float*)d_in[13];
    const float* bhh1f = (const float*)d_in[14];
    const float* Wih1b = (const float*)d_in[15];
    const float* Whh1b = (const float*)d_in[16];
    const float* bih1b = (const float*)d_in[17];
    const float* bhh1b = (const float*)d_in[18];
    const float* Wout  = (const float*)d_in[19];
    const float* bout  = (const float*)d_in[20];

    // workspace layout (floats):
    //   gbuf : G0 [V,192] (K1,K2) then gi1 [B*T,192] (K3,K4)
    //   x1   : [B,T,64]
    //   hfin : [B,64]
    float* ws   = (float*)d_ws;
    float* gbuf = ws;
    float* x1   = ws + (size_t)B_ * T_ * 192;
    float* hfin = x1 + (size_t)B_ * T_ * 64;

    // K1: vocab-factored layer-0 input gates  G0 = (embed @ Wcat0^T + b) * gsc
    gemm_gates<<<(V_ + GEMM_MT - 1) / GEMM_MT, 256, 0, stream>>>(
        embed, V_, E_, Wih0f, Wih0b, bih0f, bhh0f, bih0b, bhh0b, gbuf);

    // K2: layer-0 bidirectional scan (gathers G0[id]), writes x1
    gru_scan<1><<<2 * B_, 64, 0, stream>>>(
        gbuf, ids, mask, Whh0f, Whh0b, bhh0f, bhh0b, x1, nullptr);

    // K3: layer-1 input gates  gi1 = (x1 @ Wcat1^T + b) * gsc
    gemm_gates<<<(B_ * T_) / GEMM_MT, 256, 0, stream>>>(
        x1, B_ * T_, 64, Wih1f, Wih1b, bih1f, bhh1f, bih1b, bhh1b, gbuf);

    // K4: layer-1 scan, final hiddens only
    gru_scan<0><<<2 * B_, 64, 0, stream>>>(
        gbuf, nullptr, mask, Whh1f, Whh1b, bhh1f, bhh1b, nullptr, hfin);

    // K5: output head
    head_kernel<<<(B_ * 6 + 255) / 256, 256, 0, stream>>>(hfin, Wout, bout,
                                                          (float*)d_out);
}

// Round 4
// 482.376 us; speedup vs baseline: 1.1679x; 1.0891x over previous
//
#include <hip/hip_runtime.h>
#include <hip/hip_bf16.h>
#include <stdint.h>

#define B_ 256
#define T_ 512
#define V_ 30000
#define E_ 256
#define H_ 32

typedef float v2f __attribute__((ext_vector_type(2)));
typedef unsigned int uint2e __attribute__((ext_vector_type(2)));

#define LOG2E_F 1.44269504088896340736f

// ---------------------------------------------------------------------------
// Raw-ISA helpers
// ---------------------------------------------------------------------------
__device__ __forceinline__ float exp2_fast(float x) {      // 2^x
    float r; asm("v_exp_f32 %0, %1" : "=v"(r) : "v"(x)); return r;
}
__device__ __forceinline__ float rcp_fast(float x) {       // 1/x
    float r; asm("v_rcp_f32 %0, %1" : "=v"(r) : "v"(x)); return r;
}
// packed fp32 FMA, all-VGPR operands: acc.{lo,hi} += w.{lo,hi} * h.{lo,hi}
__device__ __forceinline__ void pk_fma(v2f& acc, v2f w, v2f h) {
    asm("v_pk_fma_f32 %0, %1, %2, %0" : "+v"(acc) : "v"(w), "v"(h));
}
// DPP lane-permute move (XOR patterns only -> direction-unambiguous)
template <int CTRL>
__device__ __forceinline__ float mdpp(float x) {
    return __int_as_float(
        __builtin_amdgcn_mov_dpp(__float_as_int(x), CTRL, 0xF, 0xF, true));
}
#define DPP_XOR1  0xB1   // quad_perm [1,0,3,2]
#define DPP_XOR2  0x4E   // quad_perm [2,3,0,1]
#define DPP_XOR3  0x1B   // quad_perm [3,2,1,0]
#define DPP_XOR7  0x141  // row_half_mirror  (i -> i^7 within 8)
#define DPP_XOR15 0x140  // row_mirror       (i -> i^15 within 16)

// value of x at lane (l ^ 32); xor-fold makes it hw-convention independent
__device__ __forceinline__ float swap32(float x) {
    uint2e r = __builtin_amdgcn_permlane32_swap(
        __float_as_uint(x), __float_as_uint(x), false, false);
    return __uint_as_float(r.x ^ r.y ^ __float_as_uint(x));
}
// value of x at lane (l ^ 16)
__device__ __forceinline__ float swap16(float x) {
    uint2e r = __builtin_amdgcn_permlane16_swap(
        __float_as_uint(x), __float_as_uint(x), false, false);
    return __uint_as_float(r.x ^ r.y ^ __float_as_uint(x));
}

// ---------------------------------------------------------------------------
// GEMM: Out[M,192] = (A[M,K] @ Wcat[192,K]^T + bias) * gate_scale
// gate_scale folds the exp->exp2 conversion: r,z gates * -log2e ; n * +2log2e
// ---------------------------------------------------------------------------
#define GEMM_MT 64
#define GEMM_KC 32
#define GEMM_PA 68
#define GEMM_PB 196

__global__ __launch_bounds__(256) void gemm_gates(
    const float* __restrict__ A, int M, int K,
    const float* __restrict__ Wf, const float* __restrict__ Wb,
    const float* __restrict__ bihf, const float* __restrict__ bhhf,
    const float* __restrict__ bihb, const float* __restrict__ bhhb,
    float* __restrict__ Out)
{
    __shared__ float As[GEMM_KC][GEMM_PA];
    __shared__ float Bs[GEMM_KC][GEMM_PB];

    const int tid = threadIdx.x;
    const int mbase = blockIdx.x * GEMM_MT;
    const int mg = tid >> 5, ng = tid & 31;
    const int m_off = mg * 8, n_off = ng * 6;

    float acc[8][6];
    #pragma unroll
    for (int r = 0; r < 8; ++r)
        #pragma unroll
        for (int c = 0; c < 6; ++c) acc[r][c] = 0.f;

    for (int kc = 0; kc < K; kc += GEMM_KC) {
        #pragma unroll
        for (int i = 0; i < 2; ++i) {
            int fi = tid + 256 * i;
            int row = fi >> 3, cf = fi & 7;
            int m = mbase + row;
            float4 v = make_float4(0.f, 0.f, 0.f, 0.f);
            if (m < M) v = *(const float4*)&A[(size_t)m * K + kc + cf * 4];
            As[cf * 4 + 0][row] = v.x; As[cf * 4 + 1][row] = v.y;
            As[cf * 4 + 2][row] = v.z; As[cf * 4 + 3][row] = v.w;
        }
        #pragma unroll
        for (int i = 0; i < 6; ++i) {
            int fi = tid + 256 * i;
            int g = fi >> 3, cf = fi & 7;
            const float* Wsel = (g < 96) ? (Wf + (size_t)g * K)
                                         : (Wb + (size_t)(g - 96) * K);
            float4 v = *(const float4*)&Wsel[kc + cf * 4];
            Bs[cf * 4 + 0][g] = v.x; Bs[cf * 4 + 1][g] = v.y;
            Bs[cf * 4 + 2][g] = v.z; Bs[cf * 4 + 3][g] = v.w;
        }
        __syncthreads();
        #pragma unroll
        for (int k = 0; k < GEMM_KC; ++k) {
            float a[8], bb[6];
            *(float4*)&a[0] = *(const float4*)&As[k][m_off];
            *(float4*)&a[4] = *(const float4*)&As[k][m_off + 4];
            *(float2*)&bb[0] = *(const float2*)&Bs[k][n_off];
            *(float2*)&bb[2] = *(const float2*)&Bs[k][n_off + 2];
            *(float2*)&bb[4] = *(const float2*)&Bs[k][n_off + 4];
            #pragma unroll
            for (int r = 0; r < 8; ++r)
                #pragma unroll
                for (int c = 0; c < 6; ++c)
                    acc[r][c] = fmaf(a[r], bb[c], acc[r][c]);
        }
        __syncthreads();
    }

    float bias[6], gsc[6];
    #pragma unroll
    for (int c = 0; c < 6; ++c) {
        int g = n_off + c;
        int g96 = (g < 96) ? g : g - 96;
        const float* bih = (g < 96) ? bihf : bihb;
        const float* bhh = (g < 96) ? bhhf : bhhb;
        bias[c] = bih[g96] + ((g96 < 64) ? bhh[g96] : 0.f);
        gsc[c]  = (g96 < 64) ? -LOG2E_F : 2.0f * LOG2E_F;
    }
    #pragma unroll
    for (int r = 0; r < 8; ++r) {
        int m = mbase + m_off + r;
        if (m < M) {
            float* op = &Out[(size_t)m * 192 + n_off];
            #pragma unroll
            for (int c = 0; c < 6; ++c) op[c] = (acc[r][c] + bias[c]) * gsc[c];
        }
    }
}

// ---------------------------------------------------------------------------
// GRU scan, K-SPLIT wave layout. One wave per (batch, direction).
// Rows (16-lane groups) hold units [L, H, L, H]:
//   lane l: i16 = l&15, row = l>>4, hi = row&1 (unit half), kh = row>>1
//   unit j = i16 + 16*hi.  Lane l and lane l^32 hold the SAME unit but
//   compute COMPLEMENTARY k-halves of all three gate dot-products.
// Per-lane weights: 3 gates x 8 v2f over 16 h-values = 48 VGPRs (was 96 --
// r0-r3 showed the allocator caps near ~100 VGPRs and rematerialized/spilled
// the 96-reg weight set EVERY step; ~48 VMEM reloads/step was the real
// ~500cy stall all broadcast variants shared).
// Seed for own k-half: rows 0,3 have it; rows 1,2 take it from l^16 (one
// permlane16_swap + cndmask). 15-op DPP XOR-butterfly distributes the 16
// seed values within each row (per-lane order folded into weight layout).
// After the matvec, one permlane32_swap per gate combines the k-halves.
// gi prefetch: 128 chunks of 4 steps, two register banks alternate per chunk.
// ---------------------------------------------------------------------------
template <int USE_IDS>
__global__ __launch_bounds__(64, 1)
__attribute__((amdgpu_waves_per_eu(1, 1)))
void gru_scan(
    const float* __restrict__ gi,     // [rows,192]: G0 (gather) or gi1 (direct)
    const int* __restrict__ ids,
    const int* __restrict__ mask,
    const float* __restrict__ Whh_f, const float* __restrict__ Whh_b,
    const float* __restrict__ bhh_f, const float* __restrict__ bhh_b,
    float* __restrict__ out_seq,      // [B,T,64] or nullptr
    float* __restrict__ out_fin)      // [B,64]   or nullptr
{
    const int l = threadIdx.x;
    const int i16 = l & 15;
    const int row = l >> 4;
    const int hi = row & 1;               // unit half
    const int kh = row >> 1;              // k half this lane computes
    const int j = i16 + 16 * hi;          // this lane's unit
    const bool lower = l < 32;            // lanes 0-31: j == l
    const bool self_seed = (hi == kh);    // rows 0,3 own their k-half seed
    const int dir = blockIdx.x & 1;
    const int b = blockIdx.x >> 1;
    const int bT = b * T_;

    const float* Whh = dir ? Whh_b : Whh_f;
    const float* bhh = dir ? bhh_b : bhh_f;

    const float sRZ = -LOG2E_F;
    const float sN2 = 2.0f * LOG2E_F;

    // butterfly value order: pair q holds seed[i16^M0[q]], seed[i16^M1[q]]
    const int M0[8] = {0, 2, 7, 5, 15, 13, 8, 10};
    const int M1[8] = {1, 3, 6, 4, 14, 12, 9, 11};

    v2f wR[8], wZ[8], wN[8];
    #pragma unroll
    for (int q = 0; q < 8; ++q) {
        const int c0 = kh * 16 + (i16 ^ M0[q]);
        const int c1 = kh * 16 + (i16 ^ M1[q]);
        wR[q] = (v2f){Whh[j * 32 + c0] * sRZ, Whh[j * 32 + c1] * sRZ};
        wZ[q] = (v2f){Whh[(32 + j) * 32 + c0] * sRZ,
                      Whh[(32 + j) * 32 + c1] * sRZ};
        wN[q] = (v2f){Whh[(64 + j) * 32 + c0] * sN2,
                      Whh[(64 + j) * 32 + c1] * sN2};
    }
    float bns = bhh[64 + j] * sN2;

    // PIN: opaque asm so the allocator keeps the (now only 48) weight regs
    // loop-resident instead of sinking the loads into the scan loop.
    #pragma unroll
    for (int q = 0; q < 8; ++q)
        asm volatile("" : "+v"(wR[q]), "+v"(wZ[q]), "+v"(wN[q]));
    asm volatile("" : "+v"(bns));

    const int offR = dir * 96 + j;
    const int offZ = dir * 96 + 32 + j;
    const int offN = dir * 96 + 64 + j;

    // int4 word base for chunk c (fwd: t=4c..4c+3; bwd: t=511-4c..508-4c)
    auto wbase = [&](int c) { return dir ? (bT + 508 - 4 * c) : (bT + 4 * c); };

    // ---- prologue ----
    int4 ids0 = make_int4(0, 0, 0, 0);
    if (USE_IDS) ids0 = *(const int4*)&ids[wbase(0)];
    int4 mask_use = *(const int4*)&mask[wbase(0)];
    int4 mask_mid = *(const int4*)&mask[wbase(1)];
    int4 mask_in  = make_int4(0, 0, 0, 0);
    int4 ids_pf = make_int4(0, 0, 0, 0), ids_mid = ids_pf, ids_in = ids_pf;
    if (USE_IDS) {
        ids_pf  = *(const int4*)&ids[wbase(1)];
        ids_mid = *(const int4*)&ids[wbase(2)];
    }

    float gR[2][4], gZ[2][4], gN[2][4];
    #pragma unroll
    for (int u = 0; u < 4; ++u) {
        int rowi;
        if (USE_IDS) {
            const int* ip = (const int*)&ids0;
            rowi = dir ? ip[3 - u] : ip[u];
        } else {
            rowi = bT + (dir ? (511 - u) : u);
        }
        const float* gp = gi + (size_t)rowi * 192;
        gR[0][u] = gp[offR];
        gZ[0][u] = gp[offZ];
        gN[0][u] = gp[offN];
    }

    float h = 0.f;

    for (int c2 = 0; c2 < 64; ++c2) {
        #pragma unroll
        for (int pb = 0; pb < 2; ++pb) {
            const int c = 2 * c2 + pb;
            // far prefetch: ids for chunk c+3, mask for chunk c+2 (clamped)
            if (USE_IDS) {
                const int ci = (c + 3 < 128) ? (c + 3) : 127;
                ids_in = *(const int4*)&ids[wbase(ci)];
            }
            {
                const int cm = (c + 2 < 128) ? (c + 2) : 127;
                mask_in = *(const int4*)&mask[wbase(cm)];
            }
            const int cN = (c + 1 < 128) ? (c + 1) : 127;  // gi prefetch chunk

            #pragma unroll
            for (int u = 0; u < 4; ++u) {
                // --- issue gi prefetch for chunk c+1, body u, into bank pb^1
                int rowN;
                if (USE_IDS) {
                    const int* ip = (const int*)&ids_pf;
                    rowN = dir ? ip[3 - u] : ip[u];
                } else {
                    rowN = bT + (dir ? (511 - 4 * cN - u) : (4 * cN + u));
                }
                const float* gpN = gi + (size_t)rowN * 192;
                gR[pb ^ 1][u] = gpN[offR];
                gZ[pb ^ 1][u] = gpN[offZ];
                gN[pb ^ 1][u] = gpN[offN];

                // --- compute step (gi bank pb, loaded during chunk c-1)
                const int* mu = (const int*)&mask_use;
                const int m = dir ? mu[3 - u] : mu[u];

                // seed = h-value of (kh*16 + i16): rows 0,3 self, rows 1,2
                // from lane l^16 (one permlane16_swap, convention-free fold)
                const float hx = swap16(h);
                const float seed = self_seed ? h : hx;

                // distribute the 16 seed values within the row (15 DPP movs)
                v2f p[8];
                p[0].x = seed;                      p[0].y = mdpp<DPP_XOR1>(seed);
                p[1].x = mdpp<DPP_XOR2>(seed);      p[1].y = mdpp<DPP_XOR3>(seed);
                p[2].x = mdpp<DPP_XOR7>(seed);      p[2].y = mdpp<DPP_XOR7>(p[0].y);
                p[3].x = mdpp<DPP_XOR7>(p[1].x);    p[3].y = mdpp<DPP_XOR7>(p[1].y);
                p[4].x = mdpp<DPP_XOR15>(seed);     p[4].y = mdpp<DPP_XOR15>(p[0].y);
                p[5].x = mdpp<DPP_XOR15>(p[1].x);   p[5].y = mdpp<DPP_XOR15>(p[1].y);
                p[6].x = mdpp<DPP_XOR15>(p[2].x);   p[6].y = mdpp<DPP_XOR15>(p[2].y);
                p[7].x = mdpp<DPP_XOR15>(p[3].x);   p[7].y = mdpp<DPP_XOR15>(p[3].y);

                // half-K matvec: 3 independent depth-8 pk_fma chains
                v2f aR = {0.f, 0.f}, aZ = {0.f, 0.f}, aN = {0.f, 0.f};
                #pragma unroll
                for (int q = 0; q < 8; ++q) {
                    pk_fma(aR, wR[q], p[q]);
                    pk_fma(aZ, wZ[q], p[q]);
                    pk_fma(aN, wN[q], p[q]);
                }
                // combine k-halves: lane l^32 holds same unit, other half
                const float sR = aR.x + aR.y;
                const float sZ = aZ.x + aZ.y;
                const float sN = aN.x + aN.y;
                const float SR = sR + swap32(sR);
                const float SZ = sZ + swap32(sZ);
                const float SN = sN + swap32(sN);

                const float yr  = gR[pb][u] + SR;
                const float yz  = gZ[pb][u] + SZ;
                const float hns = bns + SN;
                const float r = rcp_fast(1.0f + exp2_fast(yr));
                const float z = rcp_fast(1.0f + exp2_fast(yz));
                const float yn = gN[pb][u] + r * hns;
                const float n = fmaf(-2.0f, rcp_fast(1.0f + exp2_fast(yn)), 1.0f);
                const float hnew = n + z * (h - n);      // (1-z)n + z h
                h = m ? hnew : h;                        // packed-seq freeze

                if (out_seq != nullptr) {
                    const int t = dir ? (511 - 4 * c - u) : (4 * c + u);
                    if (lower)
                        out_seq[(size_t)(bT + t) * 64 + dir * 32 + j] = h;
                }
            }
            // --- rotate chunk-granular prefetch regs (1-chunk distance)
            mask_use = mask_mid; mask_mid = mask_in;
            if (USE_IDS) { ids_pf = ids_mid; ids_mid = ids_in; }
        }
    }

    if (out_fin != nullptr && lower)
        out_fin[b * 64 + dir * 32 + j] = h;
}

// ---------------------------------------------------------------------------
// Head: out[b,o] = hfin[b,:] . Wout[o,:] + bout[o]
// ---------------------------------------------------------------------------
__global__ void head_kernel(const float* __restrict__ hfin,
                            const float* __restrict__ Wout,
                            const float* __restrict__ bout,
                            float* __restrict__ out)
{
    int idx = blockIdx.x * blockDim.x + threadIdx.x;
    if (idx >= B_ * 6) return;
    int b = idx / 6, o = idx % 6;
    float acc = bout[o];
    const float* hp = hfin + b * 64;
    const float* wp = Wout + o * 64;
    #pragma unroll
    for (int k = 0; k < 64; ++k) acc = fmaf(hp[k], wp[k], acc);
    out[idx] = acc;
}

// ---------------------------------------------------------------------------
extern "C" void kernel_launch(void* const* d_in, const int* in_sizes, int n_in,
                              void* d_out, int out_size, void* d_ws, size_t ws_size,
                              hipStream_t stream)
{
    const int*   ids   = (const int*)d_in[0];
    const int*   mask  = (const int*)d_in[1];
    const float* embed = (const float*)d_in[2];
    const float* Wih0f = (const float*)d_in[3];
    const float* Whh0f = (const float*)d_in[4];
    const float* bih0f = (const float*)d_in[5];
    const float* bhh0f = (const float*)d_in[6];
    const float* Wih0b = (const float*)d_in[7];
    const float* Whh0b = (const float*)d_in[8];
    const float* bih0b = (const float*)d_in[9];
    const float* bhh0b = (const float*)d_in[10];
    const float* Wih1f = (const float*)d_in[11];
    const float* Whh1f = (const float*)d_in[12];
    const float* bih1f = (const float*)d_in[13];
    const float* bhh1f = (const float*)d_in[14];
    const float* Wih1b = (const float*)d_in[15];
    const float* Whh1b = (const float*)d_in[16];
    const float* bih1b = (const float*)d_in[17];
    const float* bhh1b = (const float*)d_in[18];
    const float* Wout  = (const float*)d_in[19];
    const float* bout  = (const float*)d_in[20];

    // workspace layout (floats):
    //   gbuf : G0 [V,192] (K1,K2) then gi1 [B*T,192] (K3,K4)
    //   x1   : [B,T,64]
    //   hfin : [B,64]
    float* ws   = (float*)d_ws;
    float* gbuf = ws;
    float* x1   = ws + (size_t)B_ * T_ * 192;
    float* hfin = x1 + (size_t)B_ * T_ * 64;

    // K1: vocab-factored layer-0 input gates  G0 = (embed @ Wcat0^T + b) * gsc
    gemm_gates<<<(V_ + GEMM_MT - 1) / GEMM_MT, 256, 0, stream>>>(
        embed, V_, E_, Wih0f, Wih0b, bih0f, bhh0f, bih0b, bhh0b, gbuf);

    // K2: layer-0 bidirectional scan (gathers G0[id]), writes x1
    gru_scan<1><<<2 * B_, 64, 0, stream>>>(
        gbuf, ids, mask, Whh0f, Whh0b, bhh0f, bhh0b, x1, nullptr);

    // K3: layer-1 input gates  gi1 = (x1 @ Wcat1^T + b) * gsc
    gemm_gates<<<(B_ * T_) / GEMM_MT, 256, 0, stream>>>(
        x1, B_ * T_, 64, Wih1f, Wih1b, bih1f, bhh1f, bih1b, bhh1b, gbuf);

    // K4: layer-1 scan, final hiddens only
    gru_scan<0><<<2 * B_, 64, 0, stream>>>(
        gbuf, nullptr, mask, Whh1f, Whh1b, bhh1f, bhh1b, nullptr, hfin);

    // K5: output head
    head_kernel<<<(B_ * 6 + 255) / 256, 256, 0, stream>>>(hfin, Wout, bout,
                                                          (float*)d_out);
}